// Round 2
// baseline (137.776 us; speedup 1.0000x reference)
//
#include <hip/hip_runtime.h>

#define T_DIM 512
#define B_DIM 128
#define E_DIM 256
#define NEG_INF (-1e30f)

typedef float vfloat4 __attribute__((ext_vector_type(4)));  // native vec for nt-store

// Closed-form stack math (exact max-plus identity):
//   rc_t[tau] = S[t] + max_{m in [tau,t]} g[m],  S = incl. prefix sum of (d-u),
//   g[m] = d[m] - S[m].
//   W[t][tau] != 0 only at right-to-left records of g (NGL chain from t),
//   truncated once S[t] + g[m] >= 1.

struct Node { float g; int ngl; };   // g value + next-greater-to-left index

// Kernel 1: per-b prep. Shuffle wave-scan for S; sparse-table (range-max
// binary descend) for NGL: fixed 10 LDS probes per thread, no divergent scans.
__global__ void __launch_bounds__(512) scan_prep(
    const float* __restrict__ u, const float* __restrict__ d,
    float* __restrict__ S_out, Node* __restrict__ nodes)
{
    const int b    = blockIdx.x;
    const int t    = threadIdx.x;
    const int lane = t & 63;
    const int w    = t >> 6;          // 8 waves

    __shared__ float wsum[8];
    __shared__ float wpre[8];
    __shared__ float M[10][T_DIM];    // M[k][i] = max g over [max(0,i-2^k+1), i]

    const float dv = d[t * B_DIM + b];
    float x = dv - u[t * B_DIM + b];

    // wave-level inclusive scan (6 shfl steps)
    #pragma unroll
    for (int off = 1; off < 64; off <<= 1) {
        float y = __shfl_up(x, off, 64);
        if (lane >= off) x += y;
    }
    if (lane == 63) wsum[w] = x;
    __syncthreads();
    if (t < 8) {                       // tiny exclusive scan of 8 wave totals
        float s = 0.f;
        for (int i = 0; i < t; ++i) s += wsum[i];
        wpre[t] = s;
    }
    __syncthreads();
    const float S = x + wpre[w];       // inclusive prefix sum of (d-u)
    const float g = dv - S;

    // build sparse table: 9 levels of doubling window max
    M[0][t] = g;
    __syncthreads();
    #pragma unroll
    for (int k = 1; k < 10; ++k) {
        int h = 1 << (k - 1);
        float left = (t >= h) ? M[k - 1][t - h] : NEG_INF;
        float mk = fmaxf(M[k - 1][t], left);
        __syncthreads();               // level k-1 reads done
        M[k][t] = mk;
        __syncthreads();
    }

    // binary descend: largest m < t with g[m] > g (strict); else -1.
    int m = t - 1;
    #pragma unroll
    for (int k = 9; k >= 0; --k) {
        if (m >= 0 && M[k][m] <= g) m -= (1 << k);
    }
    if (m < 0) m = -1;

    S_out[(b << 9) | t] = S;
    nodes[(b << 9) | t] = Node{g, m};
}

// Kernel 2: FOUR chains per wave (4x memory-level parallelism on the
// latency-bound pointer chase). Lane e-mapping: float4/lane -> 256 = E_DIM.
// Chains of one wave are 4 consecutive t of the same b: node table (4 KB/b)
// stays L1-hot and chain paths overlap heavily (shared NGL suffixes).
#define CPW 4   // chains per wave
__global__ void __launch_bounds__(256) stack_read(
    const float* __restrict__ v, const float* __restrict__ S_in,
    const Node* __restrict__ nodes, float* __restrict__ out)
{
    const int wid  = (blockIdx.x << 2) | (threadIdx.x >> 6);  // 0..16383
    const int lane = threadIdx.x & 63;
    const int e4   = lane << 2;

    float4 acc[CPW];
    float  prev[CPW], Sv[CPW];
    int    m[CPW], bb[CPW];
    bool   act[CPW];

    #pragma unroll
    for (int c = 0; c < CPW; ++c) {
        const int id = (wid << 2) | c;
        bb[c]  = id >> 9;
        m[c]   = id & 511;              // start at t
        Sv[c]  = S_in[id];
        acc[c] = make_float4(0.f, 0.f, 0.f, 0.f);
        prev[c] = 0.f;
        act[c]  = true;
    }

    while (act[0] || act[1] || act[2] || act[3]) {
        Node  nd[CPW];
        float4 vv[CPW];
        #pragma unroll
        for (int c = 0; c < CPW; ++c) {
            if (act[c]) {
                nd[c] = nodes[(bb[c] << 9) | m[c]];
                vv[c] = *(const float4*)(v + ((size_t)m[c] * B_DIM + bb[c]) * E_DIM + e4);
            }
        }
        #pragma unroll
        for (int c = 0; c < CPW; ++c) {
            if (act[c]) {
                const float rc  = Sv[c] + nd[c].g;
                const float cur = fminf(rc, 1.f);
                const float wt  = cur - prev[c];
                acc[c].x += wt * vv[c].x;
                acc[c].y += wt * vv[c].y;
                acc[c].z += wt * vv[c].z;
                acc[c].w += wt * vv[c].w;
                prev[c] = cur;
                if (rc >= 1.f || nd[c].ngl < 0) act[c] = false;
                else                            m[c] = nd[c].ngl;
            }
        }
    }

    // Non-temporal stores: keep the 64 MB write stream out of L2/L3 so v
    // stays cache-resident (v residency is what keeps FETCH_SIZE ~= v size).
    #pragma unroll
    for (int c = 0; c < CPW; ++c) {
        const int id = (wid << 2) | c;
        vfloat4 val = {acc[c].x, acc[c].y, acc[c].z, acc[c].w};
        vfloat4* o = (vfloat4*)(out + ((size_t)(id & 511) * B_DIM + (id >> 9)) * E_DIM + e4);
        __builtin_nontemporal_store(val, o);
    }
}

extern "C" void kernel_launch(void* const* d_in, const int* in_sizes, int n_in,
                              void* d_out, int out_size, void* d_ws, size_t ws_size,
                              hipStream_t stream) {
    const float* v = (const float*)d_in[0];
    const float* u = (const float*)d_in[1];
    const float* d = (const float*)d_in[2];
    float* out = (float*)d_out;

    float* S    = (float*)d_ws;                                     // 256 KB
    Node*  node = (Node*)((char*)d_ws + (size_t)B_DIM * T_DIM * 4); // 512 KB

    scan_prep<<<dim3(B_DIM), 512, 0, stream>>>(u, d, S, node);
    stack_read<<<dim3((T_DIM * B_DIM) / (CPW * 4)), 256, 0, stream>>>(v, S, node, out);
}